// Round 2
// baseline (92.259 us; speedup 1.0000x reference)
//
#include <hip/hip_runtime.h>

#define KNBR 32
#define G 8
#define OBS 16
#define KP 8          // neighbors per thread
#define TPQ 4         // threads per query
#define BLOCK 256

__global__ __launch_bounds__(BLOCK) void gib_kernel(
    const float* __restrict__ points,
    const float* __restrict__ q_coords,
    const int*   __restrict__ sidx,
    const float* __restrict__ cy_radius,
    const float* __restrict__ disk_radius,
    const float* __restrict__ disk_width,
    const float* __restrict__ cone_radius,
    const float* __restrict__ cone_inc,
    const float* __restrict__ ellip_radii,
    const float* __restrict__ lambdas,
    float* __restrict__ out,
    int M)
{
    __shared__ float s_cy[G];          // -0.5*log2e/(cy_r^2+eps)
    __shared__ float s_inc[G];
    __shared__ float s_cone[G];        // -0.5*log2e/(cone_r^2+eps)
    __shared__ float s_da[G], s_db[G]; // disk radius / width terms
    __shared__ float s_ea[G], s_eb[G], s_ec[G];
    __shared__ float s_lam[4 * G * OBS];   // (32,16) row-major

    const float NL2E = -0.5f * 1.44269504088896340736f;
    const float EPS  = 1e-8f;

    const int t = threadIdx.x;
    if (t < G) {
        float r;
        r = cy_radius[t];       s_cy[t]   = NL2E / (r * r + EPS);
        s_inc[t] = cone_inc[t];
        r = cone_radius[t];     s_cone[t] = NL2E / (r * r + EPS);
        r = disk_radius[t];     s_da[t]   = NL2E / (r * r + EPS);
        r = disk_width[t];      s_db[t]   = NL2E / (r * r + EPS);
        r = ellip_radii[3 * t + 0]; s_ea[t] = NL2E / (r * r + EPS);
        r = ellip_radii[3 * t + 1]; s_eb[t] = NL2E / (r * r + EPS);
        r = ellip_radii[3 * t + 2]; s_ec[t] = NL2E / (r * r + EPS);
    }
    s_lam[t]       = lambdas[t];
    s_lam[t + 256] = lambdas[t + 256];
    __syncthreads();

    const int gid = blockIdx.x * BLOCK + t;
    const int m   = gid >> 2;       // query index
    const int sub = t & 3;          // which quarter of K
    if (m >= M) return;

    const float qx = q_coords[3 * m + 0];
    const float qy = q_coords[3 * m + 1];
    const float qz = q_coords[3 * m + 2];

    // 8 neighbor indices, two int4 loads (group of 4 lanes covers 128B contiguous)
    const int4* ip = (const int4*)(sidx + (size_t)m * KNBR + sub * KP);
    int4 i0 = ip[0], i1 = ip[1];
    int id[KP] = {i0.x, i0.y, i0.z, i0.w, i1.x, i1.y, i1.z, i1.w};

    float x2[KP], y2[KP], z2[KP], xy2[KP], rxy[KP], zz[KP];
    const float INF = __builtin_inff();
    #pragma unroll
    for (int j = 0; j < KP; j++) {
        const float* p = points + 3 * (size_t)id[j];
        float rx = p[0] - qx, ry = p[1] - qy, rz = p[2] - qz;
        float a = rx * rx, b = ry * ry, c = rz * rz;
        float d2 = a + b + c;
        bool act = (d2 <= 1.0f);          // REACH^2 = 1
        // masked-out neighbor: drive exp2 args to -inf -> weight 0 exactly
        x2[j]  = act ? a : INF;
        y2[j]  = act ? b : INF;
        z2[j]  = act ? c : INF;
        xy2[j] = act ? (a + b) : INF;
        rxy[j] = act ? __builtin_amdgcn_sqrtf(a + b + EPS) : INF;
        zz[j]  = rz;
    }

    float acc[4 * G];
    #pragma unroll
    for (int g = 0; g < G; g++) {
        const float ccy  = s_cy[g];
        const float inc  = s_inc[g];
        const float ccn  = s_cone[g];
        const float da   = s_da[g];
        const float db   = s_db[g];
        const float ea   = s_ea[g];
        const float eb   = s_eb[g];
        const float ec   = s_ec[g];
        float a0 = 0.f, a1 = 0.f, a2 = 0.f, a3 = 0.f;
        #pragma unroll
        for (int j = 0; j < KP; j++) {
            // cylinder
            a0 += __builtin_amdgcn_exp2f(xy2[j] * ccy);
            // cone
            float d = __builtin_fmaf(-inc, zz[j], rxy[j]);
            a1 += __builtin_amdgcn_exp2f(d * d * ccn);
            // disk
            a2 += __builtin_amdgcn_exp2f(__builtin_fmaf(xy2[j], da, z2[j] * db));
            // ellipsoid
            a3 += __builtin_amdgcn_exp2f(__builtin_fmaf(x2[j], ea,
                         __builtin_fmaf(y2[j], eb, z2[j] * ec)));
        }
        acc[g]          = a0;
        acc[G + g]      = a1;
        acc[2 * G + g]  = a2;
        acc[3 * G + g]  = a3;
    }

    // reduce across the 4 lanes of this query (butterfly)
    #pragma unroll
    for (int j = 0; j < 4 * G; j++) {
        acc[j] += __shfl_xor(acc[j], 1);
        acc[j] += __shfl_xor(acc[j], 2);
    }

    // epilogue: out[m, sub*4 .. sub*4+3] = (acc . lambda[:, cols]) / K
    float o0 = 0.f, o1 = 0.f, o2 = 0.f, o3 = 0.f;
    #pragma unroll
    for (int j = 0; j < 4 * G; j++) {
        float4 l = *(const float4*)(s_lam + j * OBS + sub * 4);
        o0 = __builtin_fmaf(acc[j], l.x, o0);
        o1 = __builtin_fmaf(acc[j], l.y, o1);
        o2 = __builtin_fmaf(acc[j], l.z, o2);
        o3 = __builtin_fmaf(acc[j], l.w, o3);
    }
    const float s = 1.0f / (float)KNBR;
    float4 o = make_float4(o0 * s, o1 * s, o2 * s, o3 * s);
    *(float4*)(out + (size_t)m * OBS + sub * 4) = o;
}

extern "C" void kernel_launch(void* const* d_in, const int* in_sizes, int n_in,
                              void* d_out, int out_size, void* d_ws, size_t ws_size,
                              hipStream_t stream) {
    const float* points      = (const float*)d_in[0];
    const float* q_coords    = (const float*)d_in[1];
    const int*   sidx        = (const int*)  d_in[2];
    const float* cy_radius   = (const float*)d_in[3];
    const float* disk_radius = (const float*)d_in[4];
    const float* disk_width  = (const float*)d_in[5];
    const float* cone_radius = (const float*)d_in[6];
    const float* cone_inc    = (const float*)d_in[7];
    const float* ellip_radii = (const float*)d_in[8];
    const float* lambdas     = (const float*)d_in[9];
    float* out = (float*)d_out;

    const int M = in_sizes[1] / 3;
    const int grid = (M * TPQ + BLOCK - 1) / BLOCK;
    gib_kernel<<<grid, BLOCK, 0, stream>>>(points, q_coords, sidx,
                                           cy_radius, disk_radius, disk_width,
                                           cone_radius, cone_inc, ellip_radii,
                                           lambdas, out, M);
}